// Round 4
// baseline (1090.444 us; speedup 1.0000x reference)
//
#include <hip/hip_runtime.h>
#include <hip/hip_bf16.h>

#define D_FEAT 128

// Round 1 showed plain atomicAdd(float*) compiles to a CAS loop on gfx950
// (exactly 16 B HBM write per 4 B atomic => read+write-through per attempt).
// unsafeAtomicAdd is HIP's blessed wrapper for the native no-return
// global_atomic_add_f32 (memory-side execution, gfx90a+).
__device__ __forceinline__ void fadd_native(float* p, float v) {
    unsafeAtomicAdd(p, v);
}

// Pass 1: per-edge temporal weight w[e] = norm[e] * exp(-lam * dt[e])
__global__ void edge_weight_kernel(const float* __restrict__ dt,
                                   const float* __restrict__ norm,
                                   const float* __restrict__ decay_lam,
                                   float* __restrict__ w, int E) {
    int i = blockIdx.x * blockDim.x + threadIdx.x;
    if (i >= E) return;
    float lam = fmaxf(decay_lam[0], 0.0f) + 1e-4f;
    w[i] = norm[i] * expf(-lam * dt[i]);
}

// Pass 2: scatter-add with native atomics. 32 lanes/edge, float4/lane.
__global__ void scatter_kernel(const float* __restrict__ h,
                               const int* __restrict__ src,
                               const int* __restrict__ dst,
                               const float* __restrict__ w,
                               float* __restrict__ out, int E) {
    long long gid = (long long)blockIdx.x * blockDim.x + threadIdx.x;
    int e = (int)(gid >> 5);
    if (e >= E) return;
    int lane = (int)(gid & 31);

    int s = src[e];
    int d = dst[e];
    float we = w[e];

    const float4* hp = (const float4*)(h + (size_t)s * D_FEAT);
    float4 v = hp[lane];

    float* op = out + (size_t)d * D_FEAT + lane * 4;
    fadd_native(op + 0, v.x * we);
    fadd_native(op + 1, v.y * we);
    fadd_native(op + 2, v.z * we);
    fadd_native(op + 3, v.w * we);
}

extern "C" void kernel_launch(void* const* d_in, const int* in_sizes, int n_in,
                              void* d_out, int out_size, void* d_ws, size_t ws_size,
                              hipStream_t stream) {
    const float* h         = (const float*)d_in[0];
    const int*   src       = (const int*)d_in[1];
    const int*   dst       = (const int*)d_in[2];
    const float* dt        = (const float*)d_in[3];
    const float* norm      = (const float*)d_in[4];
    const float* decay_lam = (const float*)d_in[5];
    float* out = (float*)d_out;

    const int E = in_sizes[1];

    float* w = (float*)d_ws;  // E floats of scratch

    // Atomics accumulate into out — must start from zero (harness poisons it).
    hipMemsetAsync(out, 0, (size_t)out_size * sizeof(float), stream);

    {
        int threads = 256;
        int blocks = (E + threads - 1) / threads;
        edge_weight_kernel<<<blocks, threads, 0, stream>>>(dt, norm, decay_lam, w, E);
    }
    {
        long long total = (long long)E * 32;
        int threads = 256;
        long long blocks = (total + threads - 1) / threads;
        scatter_kernel<<<(int)blocks, threads, 0, stream>>>(h, src, dst, w, out, E);
    }
}

// Round 5
// 322.897 us; speedup vs baseline: 3.3771x; 3.3771x over previous
//
#include <hip/hip_runtime.h>
#include <hip/hip_bf16.h>

#define D_FEAT 128
#define SCAN_THREADS 1024

// ---- Pass A: per-dst degree histogram ----
__global__ void degree_kernel(const int* __restrict__ dst, int* __restrict__ deg, int E) {
    int e = blockIdx.x * blockDim.x + threadIdx.x;
    if (e >= E) return;
    atomicAdd(&deg[dst[e]], 1);
}

// ---- Pass B: single-block exclusive scan (chunk-sum -> LDS scan -> re-walk) ----
__global__ void __launch_bounds__(SCAN_THREADS)
scan_kernel(const int* __restrict__ deg, int* __restrict__ offs,
            int* __restrict__ cursor, int N) {
    __shared__ int partials[SCAN_THREADS];
    int tid = threadIdx.x;
    int chunk = (N + SCAN_THREADS - 1) / SCAN_THREADS;
    int begin = tid * chunk;
    int end = min(begin + chunk, N);
    int sum = 0;
    for (int i = begin; i < end; ++i) sum += deg[i];
    partials[tid] = sum;
    __syncthreads();
    // Hillis-Steele inclusive scan over the 1024 chunk sums
    for (int off = 1; off < SCAN_THREADS; off <<= 1) {
        int t = (tid >= off) ? partials[tid - off] : 0;
        __syncthreads();
        partials[tid] += t;
        __syncthreads();
    }
    int run = partials[tid] - sum;  // exclusive prefix of this thread's chunk
    for (int i = begin; i < end; ++i) {
        int d = deg[i];
        offs[i] = run;
        cursor[i] = run;
        run += d;
    }
}

// ---- Pass C: bucket edges by dst; fused weight; packed (src,w) pair ----
__global__ void bucket_kernel(const int* __restrict__ src, const int* __restrict__ dst,
                              const float* __restrict__ dt, const float* __restrict__ norm,
                              const float* __restrict__ decay_lam,
                              int* __restrict__ cursor,
                              float2* __restrict__ pairs, int E) {
    int e = blockIdx.x * blockDim.x + threadIdx.x;
    if (e >= E) return;
    float lam = fmaxf(decay_lam[0], 0.0f) + 1e-4f;
    float w = norm[e] * expf(-lam * dt[e]);
    int d = dst[e];
    int pos = atomicAdd(&cursor[d], 1);
    float2 p;
    p.x = __int_as_float(src[e]);
    p.y = w;
    pairs[pos] = p;  // one 8 B scattered store instead of two 4 B stores
}

// ---- Pass D: gather-accumulate. One wave (64 lanes) per node, float2/lane ----
__global__ void __launch_bounds__(256)
gather_kernel(const float* __restrict__ h,
              const int* __restrict__ offs, const int* __restrict__ deg,
              const float2* __restrict__ pairs,
              float* __restrict__ out, int N) {
    int node = blockIdx.x * 4 + (threadIdx.x >> 6);
    if (node >= N) return;
    int lane = threadIdx.x & 63;
    int start = offs[node];
    int end = start + deg[node];
    float accx = 0.0f, accy = 0.0f;
    for (int j = start; j < end; ++j) {
        float2 p = pairs[j];          // wave-uniform broadcast load
        int s = __float_as_int(p.x);
        float we = p.y;
        float2 v = ((const float2*)(h + (size_t)s * D_FEAT))[lane];
        accx += v.x * we;
        accy += v.y * we;
    }
    float2 r; r.x = accx; r.y = accy;
    ((float2*)(out + (size_t)node * D_FEAT))[lane] = r;
}

extern "C" void kernel_launch(void* const* d_in, const int* in_sizes, int n_in,
                              void* d_out, int out_size, void* d_ws, size_t ws_size,
                              hipStream_t stream) {
    const float* h         = (const float*)d_in[0];
    const int*   src       = (const int*)d_in[1];
    const int*   dst       = (const int*)d_in[2];
    const float* dt        = (const float*)d_in[3];
    const float* norm      = (const float*)d_in[4];
    const float* decay_lam = (const float*)d_in[5];
    float* out = (float*)d_out;

    const int E = in_sizes[1];
    const int N = out_size / D_FEAT;

    // workspace layout
    char* ws = (char*)d_ws;
    int*    deg    = (int*)ws;     ws += (size_t)N * 4;
    int*    offs   = (int*)ws;     ws += (size_t)N * 4;
    int*    cursor = (int*)ws;     ws += (size_t)N * 4;
    float2* pairs  = (float2*)ws;  ws += (size_t)E * 8;

    hipMemsetAsync(deg, 0, (size_t)N * 4, stream);

    {   // degree histogram
        int blocks = (E + 255) / 256;
        degree_kernel<<<blocks, 256, 0, stream>>>(dst, deg, E);
    }
    {   // exclusive scan + cursor init, one block
        scan_kernel<<<1, SCAN_THREADS, 0, stream>>>(deg, offs, cursor, N);
    }
    {   // bucket with fused weight
        int blocks = (E + 255) / 256;
        bucket_kernel<<<blocks, 256, 0, stream>>>(src, dst, dt, norm, decay_lam,
                                                  cursor, pairs, E);
    }
    {   // gather (writes every output element exactly once)
        int blocks = (N + 3) / 4;
        gather_kernel<<<blocks, 256, 0, stream>>>(h, offs, deg, pairs, out, N);
    }
}

// Round 6
// 183.454 us; speedup vs baseline: 5.9440x; 1.7601x over previous
//
#include <hip/hip_runtime.h>
#include <hip/hip_bf16.h>

#define D_FEAT 128
#define PAD 64          // padded slots per node; avg degree 12, P(>64) ~ 1e-20
#define OVF_CAP 4096    // overflow side-list capacity (expected use: 0)

// ======================= FAST PATH: padded buckets =======================

// Bucket edges into pairs[dst*PAD + pos]; cursor[dst] ends up = degree.
__global__ void bucket_pad_kernel(const int* __restrict__ src, const int* __restrict__ dst,
                                  const float* __restrict__ dt, const float* __restrict__ norm,
                                  const float* __restrict__ decay_lam,
                                  int* __restrict__ cursor, float2* __restrict__ pairs,
                                  int* __restrict__ ovf_cnt, int* __restrict__ ovf_d,
                                  int* __restrict__ ovf_s, float* __restrict__ ovf_w, int E) {
    int e = blockIdx.x * blockDim.x + threadIdx.x;
    if (e >= E) return;
    float lam = fmaxf(decay_lam[0], 0.0f) + 1e-4f;
    float w = norm[e] * expf(-lam * dt[e]);
    int d = dst[e];
    int s = src[e];
    int pos = atomicAdd(&cursor[d], 1);
    if (pos < PAD) {
        float2 p;
        p.x = __int_as_float(s);
        p.y = w;
        pairs[(size_t)d * PAD + pos] = p;
    } else {
        int o = atomicAdd(ovf_cnt, 1);
        if (o < OVF_CAP) { ovf_d[o] = d; ovf_s[o] = s; ovf_w[o] = w; }
    }
}

// One wave per node; lane holds float2 of the feature row.
__global__ void __launch_bounds__(256)
gather_pad_kernel(const float* __restrict__ h, const int* __restrict__ cursor,
                  const float2* __restrict__ pairs,
                  const int* __restrict__ ovf_cnt, const int* __restrict__ ovf_d,
                  const int* __restrict__ ovf_s, const float* __restrict__ ovf_w,
                  float* __restrict__ out, int N) {
    int node = blockIdx.x * 4 + (threadIdx.x >> 6);
    if (node >= N) return;
    int lane = threadIdx.x & 63;
    int deg = cursor[node];
    int m = min(deg, PAD);
    const float2* row = pairs + (size_t)node * PAD;
    float accx = 0.0f, accy = 0.0f;
    for (int j = 0; j < m; ++j) {
        float2 p = row[j];
        int s = __float_as_int(p.x);
        float we = p.y;
        float2 v = ((const float2*)(h + (size_t)s * D_FEAT))[lane];
        accx += v.x * we;
        accy += v.y * we;
    }
    if (deg > PAD) {  // only overflowing nodes scan the side list (expected: never)
        int oc = min(*ovf_cnt, OVF_CAP);
        for (int o = 0; o < oc; ++o) {
            if (ovf_d[o] == node) {
                float we = ovf_w[o];
                float2 v = ((const float2*)(h + (size_t)ovf_s[o] * D_FEAT))[lane];
                accx += v.x * we;
                accy += v.y * we;
            }
        }
    }
    float2 r; r.x = accx; r.y = accy;
    ((float2*)(out + (size_t)node * D_FEAT))[lane] = r;
}

// ================== FALLBACK PATH: compact CSR (round-2) ==================

__global__ void degree_kernel(const int* __restrict__ dst, int* __restrict__ deg, int E) {
    int e = blockIdx.x * blockDim.x + threadIdx.x;
    if (e >= E) return;
    atomicAdd(&deg[dst[e]], 1);
}

__global__ void scan_blocks(const int* __restrict__ deg, int* __restrict__ offs,
                            int* __restrict__ blockSums, int N) {
    __shared__ int tmp[256];
    int tid = threadIdx.x;
    int gid = blockIdx.x * 256 + tid;
    int v = (gid < N) ? deg[gid] : 0;
    tmp[tid] = v;
    __syncthreads();
    for (int off = 1; off < 256; off <<= 1) {
        int t = (tid >= off) ? tmp[tid - off] : 0;
        __syncthreads();
        tmp[tid] += t;
        __syncthreads();
    }
    if (gid < N) offs[gid] = tmp[tid] - v;
    if (tid == 255) blockSums[blockIdx.x] = tmp[255];
}

__global__ void scan_sums(int* __restrict__ blockSums, int* __restrict__ blockOffs, int nb) {
    __shared__ int tmp[256];
    int tid = threadIdx.x;
    int v = (tid < nb) ? blockSums[tid] : 0;
    tmp[tid] = v;
    __syncthreads();
    for (int off = 1; off < 256; off <<= 1) {
        int t = (tid >= off) ? tmp[tid - off] : 0;
        __syncthreads();
        tmp[tid] += t;
        __syncthreads();
    }
    if (tid < nb) blockOffs[tid] = tmp[tid] - v;
}

__global__ void scan_fixup(int* __restrict__ offs, const int* __restrict__ blockOffs,
                           int* __restrict__ cursor, int N) {
    int gid = blockIdx.x * 256 + threadIdx.x;
    if (gid >= N) return;
    int o = offs[gid] + blockOffs[blockIdx.x];
    offs[gid] = o;
    cursor[gid] = o;
}

__global__ void bucket_kernel(const int* __restrict__ src, const int* __restrict__ dst,
                              const float* __restrict__ dt, const float* __restrict__ norm,
                              const float* __restrict__ decay_lam,
                              int* __restrict__ cursor, float2* __restrict__ pairs, int E) {
    int e = blockIdx.x * blockDim.x + threadIdx.x;
    if (e >= E) return;
    float lam = fmaxf(decay_lam[0], 0.0f) + 1e-4f;
    float w = norm[e] * expf(-lam * dt[e]);
    int d = dst[e];
    int pos = atomicAdd(&cursor[d], 1);
    float2 p;
    p.x = __int_as_float(src[e]);
    p.y = w;
    pairs[pos] = p;
}

__global__ void __launch_bounds__(256)
gather_kernel(const float* __restrict__ h,
              const int* __restrict__ offs, const int* __restrict__ deg,
              const float2* __restrict__ pairs, float* __restrict__ out, int N) {
    int node = blockIdx.x * 4 + (threadIdx.x >> 6);
    if (node >= N) return;
    int lane = threadIdx.x & 63;
    int start = offs[node];
    int end = start + deg[node];
    float accx = 0.0f, accy = 0.0f;
    for (int j = start; j < end; ++j) {
        float2 p = pairs[j];
        int s = __float_as_int(p.x);
        float we = p.y;
        float2 v = ((const float2*)(h + (size_t)s * D_FEAT))[lane];
        accx += v.x * we;
        accy += v.y * we;
    }
    float2 r; r.x = accx; r.y = accy;
    ((float2*)(out + (size_t)node * D_FEAT))[lane] = r;
}

extern "C" void kernel_launch(void* const* d_in, const int* in_sizes, int n_in,
                              void* d_out, int out_size, void* d_ws, size_t ws_size,
                              hipStream_t stream) {
    const float* h         = (const float*)d_in[0];
    const int*   src       = (const int*)d_in[1];
    const int*   dst       = (const int*)d_in[2];
    const float* dt        = (const float*)d_in[3];
    const float* norm      = (const float*)d_in[4];
    const float* decay_lam = (const float*)d_in[5];
    float* out = (float*)d_out;

    const int E = in_sizes[1];
    const int N = out_size / D_FEAT;

    size_t pad_need = (size_t)N * 4            // cursor
                    + 64                       // ovf counter (padded)
                    + (size_t)OVF_CAP * 12     // ovf lists
                    + (size_t)N * PAD * 8;     // padded pairs

    if (ws_size >= pad_need) {
        // -------- fast path: 1 memset + 2 kernels --------
        char* ws = (char*)d_ws;
        int*    cursor  = (int*)ws;    ws += (size_t)N * 4;
        int*    ovf_cnt = (int*)ws;    ws += 64;
        int*    ovf_d   = (int*)ws;    ws += (size_t)OVF_CAP * 4;
        int*    ovf_s   = (int*)ws;    ws += (size_t)OVF_CAP * 4;
        float*  ovf_w   = (float*)ws;  ws += (size_t)OVF_CAP * 4;
        float2* pairs   = (float2*)ws;

        // zero cursor + ovf counter in one contiguous memset
        hipMemsetAsync(cursor, 0, (size_t)N * 4 + 64, stream);

        bucket_pad_kernel<<<(E + 255) / 256, 256, 0, stream>>>(
            src, dst, dt, norm, decay_lam, cursor, pairs,
            ovf_cnt, ovf_d, ovf_s, ovf_w, E);

        gather_pad_kernel<<<(N + 3) / 4, 256, 0, stream>>>(
            h, cursor, pairs, ovf_cnt, ovf_d, ovf_s, ovf_w, out, N);
    } else {
        // -------- fallback: compact CSR with hierarchical scan --------
        const int nb = (N + 255) / 256;
        char* ws = (char*)d_ws;
        int*    deg       = (int*)ws;     ws += (size_t)N * 4;
        int*    offs      = (int*)ws;     ws += (size_t)N * 4;
        int*    cursor    = (int*)ws;     ws += (size_t)N * 4;
        int*    blockSums = (int*)ws;     ws += 256 * 4;
        int*    blockOffs = (int*)ws;     ws += 256 * 4;
        float2* pairs     = (float2*)ws;

        hipMemsetAsync(deg, 0, (size_t)N * 4, stream);
        degree_kernel<<<(E + 255) / 256, 256, 0, stream>>>(dst, deg, E);
        scan_blocks<<<nb, 256, 0, stream>>>(deg, offs, blockSums, N);
        scan_sums<<<1, 256, 0, stream>>>(blockSums, blockOffs, nb);
        scan_fixup<<<nb, 256, 0, stream>>>(offs, blockOffs, cursor, N);
        bucket_kernel<<<(E + 255) / 256, 256, 0, stream>>>(
            src, dst, dt, norm, decay_lam, cursor, pairs, E);
        gather_kernel<<<(N + 3) / 4, 256, 0, stream>>>(h, offs, deg, pairs, out, N);
    }
}

// Round 7
// 155.595 us; speedup vs baseline: 7.0082x; 1.1791x over previous
//
#include <hip/hip_runtime.h>
#include <hip/hip_bf16.h>

#define D_FEAT 128
#define PAD 64          // padded slots per node; avg degree 12, P(>64) ~ 1e-20
#define OVF_CAP 4096    // overflow side-list capacity (expected use: 0)

// ======================= FAST PATH: padded buckets =======================

// Bucket edges into pairs[dst*PAD + pos]; cursor[dst] ends up = degree.
__global__ void bucket_pad_kernel(const int* __restrict__ src, const int* __restrict__ dst,
                                  const float* __restrict__ dt, const float* __restrict__ norm,
                                  const float* __restrict__ decay_lam,
                                  int* __restrict__ cursor, float2* __restrict__ pairs,
                                  int* __restrict__ ovf_cnt, int* __restrict__ ovf_d,
                                  int* __restrict__ ovf_s, float* __restrict__ ovf_w, int E) {
    int e = blockIdx.x * blockDim.x + threadIdx.x;
    if (e >= E) return;
    float lam = fmaxf(decay_lam[0], 0.0f) + 1e-4f;
    float w = norm[e] * expf(-lam * dt[e]);
    int d = dst[e];
    int s = src[e];
    int pos = atomicAdd(&cursor[d], 1);
    if (pos < PAD) {
        float2 p;
        p.x = __int_as_float(s);
        p.y = w;
        pairs[(size_t)d * PAD + pos] = p;
    } else {
        int o = atomicAdd(ovf_cnt, 1);
        if (o < OVF_CAP) { ovf_d[o] = d; ovf_s[o] = s; ovf_w[o] = w; }
    }
}

// One wave per node; lane holds float2 of the feature row.
// Latency fix (r7): bulk-load all pairs once (one predicated 8B/lane load),
// broadcast via shfl, then unroll h-row loads 4x so 4 independent 512 B
// gathers are in flight per loop body instead of 1.
__global__ void __launch_bounds__(256)
gather_pad_kernel(const float* __restrict__ h, const int* __restrict__ cursor,
                  const float2* __restrict__ pairs,
                  const int* __restrict__ ovf_cnt, const int* __restrict__ ovf_d,
                  const int* __restrict__ ovf_s, const float* __restrict__ ovf_w,
                  float* __restrict__ out, int N) {
    int node = blockIdx.x * 4 + (threadIdx.x >> 6);
    if (node >= N) return;
    int lane = threadIdx.x & 63;
    int deg = cursor[node];
    int m = min(deg, PAD);
    const float2* row = pairs + (size_t)node * PAD;

    // one vector load grabs this node's whole edge list across lanes
    float2 p = make_float2(0.0f, 0.0f);
    if (lane < m) p = row[lane];
    int   psrc = __float_as_int(p.x);
    float pw   = p.y;

    float accx = 0.0f, accy = 0.0f;
    int j = 0;
    for (; j + 4 <= m; j += 4) {
        int   s0 = __shfl(psrc, j + 0, 64);  float w0 = __shfl(pw, j + 0, 64);
        int   s1 = __shfl(psrc, j + 1, 64);  float w1 = __shfl(pw, j + 1, 64);
        int   s2 = __shfl(psrc, j + 2, 64);  float w2 = __shfl(pw, j + 2, 64);
        int   s3 = __shfl(psrc, j + 3, 64);  float w3 = __shfl(pw, j + 3, 64);
        float2 v0 = ((const float2*)(h + (size_t)s0 * D_FEAT))[lane];
        float2 v1 = ((const float2*)(h + (size_t)s1 * D_FEAT))[lane];
        float2 v2 = ((const float2*)(h + (size_t)s2 * D_FEAT))[lane];
        float2 v3 = ((const float2*)(h + (size_t)s3 * D_FEAT))[lane];
        accx += v0.x * w0; accy += v0.y * w0;
        accx += v1.x * w1; accy += v1.y * w1;
        accx += v2.x * w2; accy += v2.y * w2;
        accx += v3.x * w3; accy += v3.y * w3;
    }
    for (; j < m; ++j) {
        int   s = __shfl(psrc, j, 64);
        float we = __shfl(pw, j, 64);
        float2 v = ((const float2*)(h + (size_t)s * D_FEAT))[lane];
        accx += v.x * we;
        accy += v.y * we;
    }

    if (deg > PAD) {  // only overflowing nodes scan the side list (expected: never)
        int oc = min(*ovf_cnt, OVF_CAP);
        for (int o = 0; o < oc; ++o) {
            if (ovf_d[o] == node) {
                float we = ovf_w[o];
                float2 v = ((const float2*)(h + (size_t)ovf_s[o] * D_FEAT))[lane];
                accx += v.x * we;
                accy += v.y * we;
            }
        }
    }
    float2 r; r.x = accx; r.y = accy;
    ((float2*)(out + (size_t)node * D_FEAT))[lane] = r;
}

// ================== FALLBACK PATH: compact CSR (round-2) ==================

__global__ void degree_kernel(const int* __restrict__ dst, int* __restrict__ deg, int E) {
    int e = blockIdx.x * blockDim.x + threadIdx.x;
    if (e >= E) return;
    atomicAdd(&deg[dst[e]], 1);
}

__global__ void scan_blocks(const int* __restrict__ deg, int* __restrict__ offs,
                            int* __restrict__ blockSums, int N) {
    __shared__ int tmp[256];
    int tid = threadIdx.x;
    int gid = blockIdx.x * 256 + tid;
    int v = (gid < N) ? deg[gid] : 0;
    tmp[tid] = v;
    __syncthreads();
    for (int off = 1; off < 256; off <<= 1) {
        int t = (tid >= off) ? tmp[tid - off] : 0;
        __syncthreads();
        tmp[tid] += t;
        __syncthreads();
    }
    if (gid < N) offs[gid] = tmp[tid] - v;
    if (tid == 255) blockSums[blockIdx.x] = tmp[255];
}

__global__ void scan_sums(int* __restrict__ blockSums, int* __restrict__ blockOffs, int nb) {
    __shared__ int tmp[256];
    int tid = threadIdx.x;
    int v = (tid < nb) ? blockSums[tid] : 0;
    tmp[tid] = v;
    __syncthreads();
    for (int off = 1; off < 256; off <<= 1) {
        int t = (tid >= off) ? tmp[tid - off] : 0;
        __syncthreads();
        tmp[tid] += t;
        __syncthreads();
    }
    if (tid < nb) blockOffs[tid] = tmp[tid] - v;
}

__global__ void scan_fixup(int* __restrict__ offs, const int* __restrict__ blockOffs,
                           int* __restrict__ cursor, int N) {
    int gid = blockIdx.x * 256 + threadIdx.x;
    if (gid >= N) return;
    int o = offs[gid] + blockOffs[blockIdx.x];
    offs[gid] = o;
    cursor[gid] = o;
}

__global__ void bucket_kernel(const int* __restrict__ src, const int* __restrict__ dst,
                              const float* __restrict__ dt, const float* __restrict__ norm,
                              const float* __restrict__ decay_lam,
                              int* __restrict__ cursor, float2* __restrict__ pairs, int E) {
    int e = blockIdx.x * blockDim.x + threadIdx.x;
    if (e >= E) return;
    float lam = fmaxf(decay_lam[0], 0.0f) + 1e-4f;
    float w = norm[e] * expf(-lam * dt[e]);
    int d = dst[e];
    int pos = atomicAdd(&cursor[d], 1);
    float2 p;
    p.x = __int_as_float(src[e]);
    p.y = w;
    pairs[pos] = p;
}

__global__ void __launch_bounds__(256)
gather_kernel(const float* __restrict__ h,
              const int* __restrict__ offs, const int* __restrict__ deg,
              const float2* __restrict__ pairs, float* __restrict__ out, int N) {
    int node = blockIdx.x * 4 + (threadIdx.x >> 6);
    if (node >= N) return;
    int lane = threadIdx.x & 63;
    int start = offs[node];
    int end = start + deg[node];
    float accx = 0.0f, accy = 0.0f;
    for (int j = start; j < end; ++j) {
        float2 p = pairs[j];
        int s = __float_as_int(p.x);
        float we = p.y;
        float2 v = ((const float2*)(h + (size_t)s * D_FEAT))[lane];
        accx += v.x * we;
        accy += v.y * we;
    }
    float2 r; r.x = accx; r.y = accy;
    ((float2*)(out + (size_t)node * D_FEAT))[lane] = r;
}

extern "C" void kernel_launch(void* const* d_in, const int* in_sizes, int n_in,
                              void* d_out, int out_size, void* d_ws, size_t ws_size,
                              hipStream_t stream) {
    const float* h         = (const float*)d_in[0];
    const int*   src       = (const int*)d_in[1];
    const int*   dst       = (const int*)d_in[2];
    const float* dt        = (const float*)d_in[3];
    const float* norm      = (const float*)d_in[4];
    const float* decay_lam = (const float*)d_in[5];
    float* out = (float*)d_out;

    const int E = in_sizes[1];
    const int N = out_size / D_FEAT;

    size_t pad_need = (size_t)N * 4            // cursor
                    + 64                       // ovf counter (padded)
                    + (size_t)OVF_CAP * 12     // ovf lists
                    + (size_t)N * PAD * 8;     // padded pairs

    if (ws_size >= pad_need) {
        // -------- fast path: 1 memset + 2 kernels --------
        char* ws = (char*)d_ws;
        int*    cursor  = (int*)ws;    ws += (size_t)N * 4;
        int*    ovf_cnt = (int*)ws;    ws += 64;
        int*    ovf_d   = (int*)ws;    ws += (size_t)OVF_CAP * 4;
        int*    ovf_s   = (int*)ws;    ws += (size_t)OVF_CAP * 4;
        float*  ovf_w   = (float*)ws;  ws += (size_t)OVF_CAP * 4;
        float2* pairs   = (float2*)ws;

        // zero cursor + ovf counter in one contiguous memset
        hipMemsetAsync(cursor, 0, (size_t)N * 4 + 64, stream);

        bucket_pad_kernel<<<(E + 255) / 256, 256, 0, stream>>>(
            src, dst, dt, norm, decay_lam, cursor, pairs,
            ovf_cnt, ovf_d, ovf_s, ovf_w, E);

        gather_pad_kernel<<<(N + 3) / 4, 256, 0, stream>>>(
            h, cursor, pairs, ovf_cnt, ovf_d, ovf_s, ovf_w, out, N);
    } else {
        // -------- fallback: compact CSR with hierarchical scan --------
        const int nb = (N + 255) / 256;
        char* ws = (char*)d_ws;
        int*    deg       = (int*)ws;     ws += (size_t)N * 4;
        int*    offs      = (int*)ws;     ws += (size_t)N * 4;
        int*    cursor    = (int*)ws;     ws += (size_t)N * 4;
        int*    blockSums = (int*)ws;     ws += 256 * 4;
        int*    blockOffs = (int*)ws;     ws += 256 * 4;
        float2* pairs     = (float2*)ws;

        hipMemsetAsync(deg, 0, (size_t)N * 4, stream);
        degree_kernel<<<(E + 255) / 256, 256, 0, stream>>>(dst, deg, E);
        scan_blocks<<<nb, 256, 0, stream>>>(deg, offs, blockSums, N);
        scan_sums<<<1, 256, 0, stream>>>(blockSums, blockOffs, nb);
        scan_fixup<<<nb, 256, 0, stream>>>(offs, blockOffs, cursor, N);
        bucket_kernel<<<(E + 255) / 256, 256, 0, stream>>>(
            src, dst, dt, norm, decay_lam, cursor, pairs, E);
        gather_kernel<<<(N + 3) / 4, 256, 0, stream>>>(h, offs, deg, pairs, out, N);
    }
}